// Round 1
// baseline (250.530 us; speedup 1.0000x reference)
//
#include <hip/hip_runtime.h>
#include <hip/hip_bf16.h>
#include <math.h>

using bf16x8 = __attribute__((ext_vector_type(8))) short;
using f32x4  = __attribute__((ext_vector_type(4))) float;

#define MFMA16(a,b,c) __builtin_amdgcn_mfma_f32_16x16x32_bf16(a,b,c,0,0,0)

static __device__ __forceinline__ short f2bf(float f) {
    __hip_bfloat16 h = __float2bfloat16(f);
    return *reinterpret_cast<short*>(&h);
}

// ---------------- prep: fp32 -> bf16 casts (grid-stride over float4 units) ----------------
__global__ void prep_cast(const float* q, const float* k, const float* v,
                          const float* wq, const float* wk, const float* wv, const float* wo,
                          short* xq, short* xk, short* xv,
                          short* bwq, short* bwk, short* bwv, short* bwo) {
    const long NBIG = 1L << 20;   // 4M elems / 4
    const long NW   = 1L << 18;   // 1M elems / 4
    const long total = 3*NBIG + 4*NW;
    for (long i = (long)blockIdx.x*blockDim.x + threadIdx.x; i < total; i += (long)gridDim.x*blockDim.x) {
        const float* src; short* dst; long j = i;
        if (j < NBIG)              { src = q;  dst = xq;  }
        else if ((j -= NBIG) < NBIG) { src = k;  dst = xk;  }
        else if ((j -= NBIG) < NBIG) { src = v;  dst = xv;  }
        else if ((j -= NBIG) < NW)   { src = wq; dst = bwq; }
        else if ((j -= NW) < NW)     { src = wk; dst = bwk; }
        else if ((j -= NW) < NW)     { src = wv; dst = bwv; }
        else { j -= NW;              src = wo; dst = bwo; }
        float4 f = reinterpret_cast<const float4*>(src)[j];
        ushort4 o;
        o.x = (ushort)f2bf(f.x); o.y = (ushort)f2bf(f.y);
        o.z = (ushort)f2bf(f.z); o.w = (ushort)f2bf(f.w);
        reinterpret_cast<ushort4*>(dst)[j] = o;
    }
}

// ---------------- RoPE tables, fp64 for accuracy: cos/sin[s][j], j=0..31 ----------------
__global__ void rope_table(float* cost, float* sint) {
    int i = blockIdx.x*blockDim.x + threadIdx.x;   // 0..65535
    int s = i >> 5, j = i & 31;
    double inv = pow(10000.0, -(double)j / 32.0);
    double a = (double)s * inv;
    cost[i] = (float)cos(a);
    sint[i] = (float)sin(a);
}

// ---------------- shared 128x128x(K=1024) bf16 GEMM core: C = A * B^T ----------------
// A: [4096][1024] bf16 row-major, B: [1024][1024] bf16 row-major (used as B^T)
__device__ __forceinline__ void gemm_tile(const short* A, const short* B,
                                          int brow, int bcol, f32x4 (&acc)[4][4]) {
    __shared__ __align__(16) short Al[128*32];
    __shared__ __align__(16) short Bl[128*32];
    const int t = threadIdx.x;
    const int l = t & 63, qi = l & 15, h = l >> 4;
    const int w = t >> 6, wr = w >> 1, wc = w & 1;
    const f32x4 z4 = {0.f, 0.f, 0.f, 0.f};
#pragma unroll
    for (int i = 0; i < 4; ++i)
#pragma unroll
        for (int j = 0; j < 4; ++j) acc[i][j] = z4;

    for (int kt = 0; kt < 32; ++kt) {
        __syncthreads();
#pragma unroll
        for (int cc = 0; cc < 2; ++cc) {
            int c = t + (cc << 8);               // 0..511
            int row = c >> 2, off = (c & 3) << 3;
            int4 va = *(const int4*)(A + (long)(brow + row)*1024 + (kt << 5) + off);
            int4 vb = *(const int4*)(B + (long)(bcol + row)*1024 + (kt << 5) + off);
            *(int4*)(Al + (c << 3)) = va;
            *(int4*)(Bl + (c << 3)) = vb;
        }
        __syncthreads();
        bf16x8 af[4], bfr[4];
#pragma unroll
        for (int mf = 0; mf < 4; ++mf)
            af[mf] = *(const bf16x8*)(Al + (wr*64 + mf*16 + qi)*32 + h*8);
#pragma unroll
        for (int nf = 0; nf < 4; ++nf)
            bfr[nf] = *(const bf16x8*)(Bl + (wc*64 + nf*16 + qi)*32 + h*8);
#pragma unroll
        for (int mf = 0; mf < 4; ++mf)
#pragma unroll
            for (int nf = 0; nf < 4; ++nf)
                acc[mf][nf] = MFMA16(af[mf], bfr[nf], acc[mf][nf]);
    }
}

// ---------------- QKV projection GEMM; z selects Q/K/V; fused bias + RoPE (+1/8 into Q) ----------------
__global__ __launch_bounds__(256, 2)
void gemm_qkv_kernel(const short* xq, const short* xk, const short* xv,
                     const short* wq, const short* wk, const short* wv,
                     const float* biq, const float* bik, const float* biv,
                     short* qo, short* ko, short* vo,
                     const float* cost, const float* sint) {
    const int mode = blockIdx.z;
    const short* A    = mode == 0 ? xq  : (mode == 1 ? xk  : xv);
    const short* B    = mode == 0 ? wq  : (mode == 1 ? wk  : wv);
    const float* bias = mode == 0 ? biq : (mode == 1 ? bik : biv);
    const int brow = blockIdx.x * 128, bcol = blockIdx.y * 128;
    f32x4 acc[4][4];
    gemm_tile(A, B, brow, bcol, acc);

    const int t = threadIdx.x;
    const int l = t & 63, qi = l & 15, h = l >> 4;
    const int w = t >> 6, wr = w >> 1, wc = w & 1;
    const int n0 = bcol + wc*64, m0 = brow + wr*64;

    if (mode < 2) {
        short* dst = mode == 0 ? qo : ko;
        const float sc = (mode == 0) ? 0.125f : 1.0f;   // fold 1/sqrt(Hd) into q
#pragma unroll
        for (int nf = 0; nf < 2; ++nf) {
            const int j = nf*16 + qi;                   // rope index 0..31 within head
            const float b0 = bias[n0 + nf*16 + qi];
            const float b1 = bias[n0 + (nf+2)*16 + qi];
#pragma unroll
            for (int mf = 0; mf < 4; ++mf) {
#pragma unroll
                for (int r = 0; r < 4; ++r) {
                    int m = m0 + mf*16 + 4*h + r;
                    int s = m & 2047;
                    float c  = cost[s*32 + j];
                    float si = sint[s*32 + j];
                    float x0 = acc[mf][nf  ][r] + b0;
                    float x1 = acc[mf][nf+2][r] + b1;
                    dst[(long)m*1024 + n0 + nf*16 + qi]      = f2bf((x0*c - x1*si) * sc);
                    dst[(long)m*1024 + n0 + (nf+2)*16 + qi]  = f2bf((x1*c + x0*si) * sc);
                }
            }
        }
    } else {
        // V: store transposed as [b][h][d][s] bf16, pack 4 consecutive s
#pragma unroll
        for (int mf = 0; mf < 4; ++mf) {
#pragma unroll
            for (int nf = 0; nf < 4; ++nf) {
                int col = n0 + nf*16 + qi;
                float bb = bias[col];
                int mbase = m0 + mf*16 + 4*h;
                int bb_  = mbase >> 11, s0 = mbase & 2047;
                int hh = col >> 6, d = col & 63;
                ushort4 pk;
                pk.x = (ushort)f2bf(acc[mf][nf][0] + bb);
                pk.y = (ushort)f2bf(acc[mf][nf][1] + bb);
                pk.z = (ushort)f2bf(acc[mf][nf][2] + bb);
                pk.w = (ushort)f2bf(acc[mf][nf][3] + bb);
                *(ushort4*)(vo + (long)((bb_*16 + hh)*64 + d)*2048 + s0) = pk;
            }
        }
    }
}

// ---------------- O projection GEMM -> fp32 out ----------------
__global__ __launch_bounds__(256, 2)
void gemm_o_kernel(const short* A, const short* B, const float* bias, float* out) {
    const int brow = blockIdx.x * 128, bcol = blockIdx.y * 128;
    f32x4 acc[4][4];
    gemm_tile(A, B, brow, bcol, acc);
    const int t = threadIdx.x;
    const int l = t & 63, qi = l & 15, h = l >> 4;
    const int w = t >> 6, wr = w >> 1, wc = w & 1;
    const int n0 = bcol + wc*64, m0 = brow + wr*64;
#pragma unroll
    for (int nf = 0; nf < 4; ++nf) {
        float bb = bias[n0 + nf*16 + qi];
#pragma unroll
        for (int mf = 0; mf < 4; ++mf) {
#pragma unroll
            for (int r = 0; r < 4; ++r) {
                int m = m0 + mf*16 + 4*h + r;
                out[(long)m*1024 + n0 + nf*16 + qi] = acc[mf][nf][r] + bb;
            }
        }
    }
}

// ---------------- flash attention ----------------
// q,k: [b][s][h][d] bf16 (q pre-scaled by 1/8). vT: [b][h][d][s] bf16. out: [b][s][h][d] bf16.
// Block: 128 Q rows of one (b,h). 4 waves x 32 rows. KV tiles of 64.
// Swapped QK^T (mfma(K, Q^T)) -> lane q holds softmax rows locally; P via swizzled LDS.
__global__ __launch_bounds__(256, 2)
void attn_kernel(const short* qw, const short* kw, const short* vtw, short* ow) {
    __shared__ __align__(16) short Kl[64*64];
    __shared__ __align__(16) short Vl[64*64];
    __shared__ __align__(16) short Pl[4][32*64];
    const int t = threadIdx.x;
    const int w = t >> 6, l = t & 63, qi = l & 15, h = l >> 4;
    const int b = blockIdx.z, hh = blockIdx.y;
    const long qrow0 = (long)b*2048 + blockIdx.x*128 + w*32;
    short* myP = &Pl[w][0];

    bf16x8 bqf[2][2];
#pragma unroll
    for (int nf = 0; nf < 2; ++nf)
#pragma unroll
        for (int kf = 0; kf < 2; ++kf)
            bqf[nf][kf] = *(const bf16x8*)(qw + (qrow0 + nf*16 + qi)*1024 + hh*64 + kf*32 + h*8);

    const f32x4 z4 = {0.f, 0.f, 0.f, 0.f};
    f32x4 o[2][4];
#pragma unroll
    for (int mi = 0; mi < 2; ++mi)
#pragma unroll
        for (int nd = 0; nd < 4; ++nd) o[mi][nd] = z4;
    float mrun[2] = {-INFINITY, -INFINITY};
    float lrun[2] = {0.f, 0.f};

    const short* Kg = kw  + (long)b*2048*1024 + hh*64;
    const short* Vg = vtw + (long)(b*16 + hh)*64*2048;

    for (int jt = 0; jt < 32; ++jt) {
        __syncthreads();
#pragma unroll
        for (int cc = 0; cc < 2; ++cc) {
            int c  = t + (cc << 8);            // 0..511
            int r0 = c >> 3, e0 = (c & 7) << 3;
            int4 kv = *(const int4*)(Kg + (long)(jt*64 + r0)*1024 + e0);
            int4 vv = *(const int4*)(Vg + (long)r0*2048 + jt*64 + e0);
            *(int4*)((char*)Kl + (((r0*64 + e0)*2) ^ ((r0 & 7) << 4))) = kv;
            *(int4*)((char*)Vl + (((r0*64 + e0)*2) ^ ((r0 & 7) << 4))) = vv;
        }
        __syncthreads();

        // S^T = K * Q^T : C row = j-local (4h+r+16mf), col = i-local (qi+16nf)
        f32x4 sc[4][2];
#pragma unroll
        for (int mf = 0; mf < 4; ++mf) { sc[mf][0] = z4; sc[mf][1] = z4; }
#pragma unroll
        for (int kf = 0; kf < 2; ++kf) {
#pragma unroll
            for (int mf = 0; mf < 4; ++mf) {
                bf16x8 ka = *(const bf16x8*)((char*)Kl +
                    ((((mf*16 + qi)*64 + kf*32 + h*8)*2) ^ ((qi & 7) << 4)));
                sc[mf][0] = MFMA16(ka, bqf[0][kf], sc[mf][0]);
                sc[mf][1] = MFMA16(ka, bqf[1][kf], sc[mf][1]);
            }
        }

        float csc[2];
#pragma unroll
        for (int nf = 0; nf < 2; ++nf) {
            float tm = -INFINITY;
#pragma unroll
            for (int mf = 0; mf < 4; ++mf)
#pragma unroll
                for (int r = 0; r < 4; ++r) tm = fmaxf(tm, sc[mf][nf][r]);
            tm = fmaxf(tm, __shfl_xor(tm, 16));
            tm = fmaxf(tm, __shfl_xor(tm, 32));
            float mnew = fmaxf(mrun[nf], tm);
            float corr = __expf(mrun[nf] - mnew);
            float ts = 0.f;
#pragma unroll
            for (int mf = 0; mf < 4; ++mf) {
                float p0 = __expf(sc[mf][nf][0] - mnew);
                float p1 = __expf(sc[mf][nf][1] - mnew);
                float p2 = __expf(sc[mf][nf][2] - mnew);
                float p3 = __expf(sc[mf][nf][3] - mnew);
                ts += p0 + p1 + p2 + p3;
                ushort4 pk;
                pk.x = (ushort)f2bf(p0); pk.y = (ushort)f2bf(p1);
                pk.z = (ushort)f2bf(p2); pk.w = (ushort)f2bf(p3);
                *(ushort4*)((char*)myP +
                    ((((nf*16 + qi)*64 + mf*16 + 4*h)*2) ^ ((qi & 7) << 4))) = pk;
            }
            ts += __shfl_xor(ts, 16);
            ts += __shfl_xor(ts, 32);
            lrun[nf] = lrun[nf]*corr + ts;
            mrun[nf] = mnew;
            csc[nf] = corr;
        }

        // rescale O: factor for row i = mi*16+4h+r lives on lane with qi == 4h+r
#pragma unroll
        for (int mi = 0; mi < 2; ++mi)
#pragma unroll
            for (int r = 0; r < 4; ++r) {
                float f = __shfl(csc[mi], 4*h + r);
#pragma unroll
                for (int nd = 0; nd < 4; ++nd) o[mi][nd][r] *= f;
            }

        // O += P * V  (A=P from LDS, B=V^T from LDS)
#pragma unroll
        for (int kf = 0; kf < 2; ++kf) {
            bf16x8 pa[2], vb[4];
#pragma unroll
            for (int mi = 0; mi < 2; ++mi)
                pa[mi] = *(const bf16x8*)((char*)myP +
                    ((((mi*16 + qi)*64 + kf*32 + h*8)*2) ^ ((qi & 7) << 4)));
#pragma unroll
            for (int nd = 0; nd < 4; ++nd)
                vb[nd] = *(const bf16x8*)((char*)Vl +
                    ((((nd*16 + qi)*64 + kf*32 + h*8)*2) ^ ((qi & 7) << 4)));
#pragma unroll
            for (int mi = 0; mi < 2; ++mi)
#pragma unroll
                for (int nd = 0; nd < 4; ++nd)
                    o[mi][nd] = MFMA16(pa[mi], vb[nd], o[mi][nd]);
        }
    }

    float rinv[2] = {1.f/lrun[0], 1.f/lrun[1]};
#pragma unroll
    for (int mi = 0; mi < 2; ++mi)
#pragma unroll
        for (int r = 0; r < 4; ++r) {
            float f = __shfl(rinv[mi], 4*h + r);
#pragma unroll
            for (int nd = 0; nd < 4; ++nd)
                ow[(qrow0 + mi*16 + 4*h + r)*1024 + hh*64 + nd*16 + qi] =
                    f2bf(o[mi][nd][r] * f);
        }
}

// ---------------- launch ----------------
extern "C" void kernel_launch(void* const* d_in, const int* in_sizes, int n_in,
                              void* d_out, int out_size, void* d_ws, size_t ws_size,
                              hipStream_t stream) {
    const float* query = (const float*)d_in[0];
    const float* key_  = (const float*)d_in[1];
    const float* value = (const float*)d_in[2];
    const float* Wq = (const float*)d_in[3];
    const float* bq = (const float*)d_in[4];
    const float* Wk = (const float*)d_in[5];
    const float* bk = (const float*)d_in[6];
    const float* Wv = (const float*)d_in[7];
    const float* bv = (const float*)d_in[8];
    const float* Wo = (const float*)d_in[9];
    const float* bo = (const float*)d_in[10];
    float* out = (float*)d_out;

    char* ws = (char*)d_ws;
    const size_t MB = 1u << 20;
    short* xq  = (short*)(ws);              // 8 MB  [4096][1024] bf16
    short* xk  = (short*)(ws + 8*MB);
    short* xv  = (short*)(ws + 16*MB);
    short* wqb = (short*)(ws + 24*MB);      // 2 MB each
    short* wkb = (short*)(ws + 26*MB);
    short* wvb = (short*)(ws + 28*MB);
    short* wob = (short*)(ws + 30*MB);
    short* qws = (short*)(ws + 32*MB);      // [b][s][h][d] bf16, q pre-scaled
    short* kws = (short*)(ws + 40*MB);      // [b][s][h][d]
    short* vtw = (short*)(ws + 48*MB);      // [b][h][d][s]
    float* cost = (float*)(ws + 56*MB);     // [2048][32]
    float* sint = (float*)(ws + 56*MB + 2048*32*4);
    short* attn = xq;                       // alias: xq dead after projections

    hipLaunchKernelGGL(prep_cast, dim3(2048), dim3(256), 0, stream,
                       query, key_, value, Wq, Wk, Wv, Wo,
                       xq, xk, xv, wqb, wkb, wvb, wob);
    hipLaunchKernelGGL(rope_table, dim3(256), dim3(256), 0, stream, cost, sint);
    hipLaunchKernelGGL(gemm_qkv_kernel, dim3(32, 8, 3), dim3(256), 0, stream,
                       xq, xk, xv, wqb, wkb, wvb, bq, bk, bv,
                       qws, kws, vtw, cost, sint);
    hipLaunchKernelGGL(attn_kernel, dim3(16, 16, 2), dim3(256), 0, stream,
                       qws, kws, vtw, attn);
    hipLaunchKernelGGL(gemm_o_kernel, dim3(32, 8), dim3(256), 0, stream,
                       attn, wob, bo, out);
}